// Round 8
// baseline (231.810 us; speedup 1.0000x reference)
//
#include <hip/hip_runtime.h>

#define DT 0.03f
#define SEQ_LEN 30
#define D_STEER (0.4f * 0.03f)

#define BT 64            // threads per block (one wave) == rows per tile
#define PAD 31           // float4 stride per row in LDS (30 + 1 pad)

typedef float f32x2 __attribute__((ext_vector_type(2)));
typedef float f32x4 __attribute__((ext_vector_type(4)));

__global__ __launch_bounds__(64) void ccdec_kernel(
    const float* __restrict__ z,
    const float* __restrict__ init_state,
    float* __restrict__ out,
    int B, int ntiles, int grid)
{
    // Single-wave block: NO __syncthreads anywhere. DS ops from one wave
    // execute in order; compiler's lgkmcnt waits handle LDS ordering.
    // This keeps global stores in flight across loop iterations (no
    // vmcnt(0) drain like a barrier would force).
    __shared__ f32x4 lds[BT * PAD];   // 31744 B -> 5 blocks/CU

    const int tid = threadIdx.x;

    // consecutive chunk of tiles per block (linear output stream per block)
    int t0 = (int)(((long long)blockIdx.x       * ntiles) / grid);
    int t1 = (int)(((long long)(blockIdx.x + 1) * ntiles) / grid);
    if (t0 >= t1) return;

    // ---- prefetch first tile's inputs ----
    int b0  = t0 * BT + tid;
    int bb0 = (b0 < B) ? b0 : (B - 1);
    f32x2 zv  = *(reinterpret_cast<const f32x2*>(z) + (size_t)bb0);
    const f32x2* stp0 = reinterpret_cast<const f32x2*>(init_state) + 3ull * (size_t)bb0;
    f32x2 s01 = stp0[0];
    f32x2 s23 = stp0[1];
    f32x2 s45 = stp0[2];

    for (int tile = t0; tile < t1; ++tile) {
        // ---- unpack current tile's inputs ----
        float x   = s01.x;
        float y   = s01.y;
        float psi = s23.x;
        float v   = s23.y;
        float last_st = s45.y;   // init_state[:,5]

        // ---- steering / pedal preamble (mirror clip_by_tensor semantics) ----
        float steering = zv.y * 0.5f;
        float tmin = last_st - D_STEER;
        float tmax = last_st + D_STEER;
        float r = (steering > tmin) ? steering : ((steering < tmin) ? tmin : 0.0f);
        r = (r <= tmax) ? r : tmax;
        steering = fminf(fmaxf(r, -0.5f), 0.5f);

        float pedal = zv.x * 2.5f;
        float beta  = fminf(fmaxf(steering, -0.5f), 0.5f);
        float a_t   = fminf(fmaxf(pedal, -2.5f), 2.5f);
        float tan_beta = __tanf(beta);
        float dpsi_k   = tan_beta * (1.0f / 2.5f) * DT;
        float adt      = a_t * DT;

        bool full_tile = ((tile + 1) * BT <= B);

        if (full_tile) {
            // ---- compute all 30 steps into LDS (full rows) ----
            #pragma unroll
            for (int t = 0; t < SEQ_LEN; ++t) {
                float v1 = fminf(fmaxf(v + adt, 0.0f), 10.0f);
                psi = v * dpsi_k + psi;          // uses OLD v
                float s, c;
                __sincosf(psi, &s, &c);
                x = v1 * c * DT + x;
                y = v1 * s * DT + y;
                v = v1;
                f32x4 o; o.x = x; o.y = y; o.z = psi; o.w = v;
                lds[tid * PAD + t] = o;
            }

            // ---- prefetch NEXT tile's inputs BEFORE the store burst ----
            // (loads issued ahead of the 30 stores -> compiler waits with
            //  vmcnt(~30), never a full drain; latency hides under stores)
            if (tile + 1 < t1) {
                int nb  = (tile + 1) * BT + tid;
                int nbb = (nb < B) ? nb : (B - 1);
                zv  = *(reinterpret_cast<const f32x2*>(z) + (size_t)nbb);
                const f32x2* nstp = reinterpret_cast<const f32x2*>(init_state) + 3ull * (size_t)nbb;
                s01 = nstp[0];
                s23 = nstp[1];
                s45 = nstp[2];
            }

            // ---- stream tile out flat: every wave store = 16 full lines ----
            f32x4* outp4 = reinterpret_cast<f32x4*>(out) + (size_t)tile * BT * SEQ_LEN;
            #pragma unroll
            for (int m = 0; m < SEQ_LEN; ++m) {
                int f  = tid + m * BT;           // 0 .. 1919, contiguous per wave
                int rr = f / SEQ_LEN;            // row within tile
                int jj = f - rr * SEQ_LEN;       // step
                outp4[f] = lds[rr * PAD + jj];
            }
        } else {
            // partial tile (never hit for B % 64 == 0): direct stores
            int wb = tile * BT + tid;
            if (wb < B) {
                f32x4* outp = reinterpret_cast<f32x4*>(out) + (size_t)wb * SEQ_LEN;
                #pragma unroll
                for (int t = 0; t < SEQ_LEN; ++t) {
                    float v1 = fminf(fmaxf(v + adt, 0.0f), 10.0f);
                    psi = v * dpsi_k + psi;
                    float s, c;
                    __sincosf(psi, &s, &c);
                    x = v1 * c * DT + x;
                    y = v1 * s * DT + y;
                    v = v1;
                    f32x4 o; o.x = x; o.y = y; o.z = psi; o.w = v;
                    outp[t] = o;
                }
            }
            // refill prefetch regs for the next iteration (rare path)
            if (tile + 1 < t1) {
                int nb  = (tile + 1) * BT + tid;
                int nbb = (nb < B) ? nb : (B - 1);
                zv  = *(reinterpret_cast<const f32x2*>(z) + (size_t)nbb);
                const f32x2* nstp = reinterpret_cast<const f32x2*>(init_state) + 3ull * (size_t)nbb;
                s01 = nstp[0];
                s23 = nstp[1];
                s45 = nstp[2];
            }
        }
    }
}

extern "C" void kernel_launch(void* const* d_in, const int* in_sizes, int n_in,
                              void* d_out, int out_size, void* d_ws, size_t ws_size,
                              hipStream_t stream)
{
    const float* z          = (const float*)d_in[0];   // (B, 2) f32
    const float* init_state = (const float*)d_in[1];   // (B, 6) f32
    float* out = (float*)d_out;                        // (B, 30, 4) f32

    int B = in_sizes[0] / 2;
    int ntiles = (B + BT - 1) / BT;
    int grid = 256 * 5;                 // 5 resident 1-wave blocks per CU
    if (grid > ntiles) grid = ntiles;
    ccdec_kernel<<<grid, BT, 0, stream>>>(z, init_state, out, B, ntiles, grid);
}

// Round 9
// 187.608 us; speedup vs baseline: 1.2356x; 1.2356x over previous
//
#include <hip/hip_runtime.h>

#define DT 0.03f
#define SEQ_LEN 30
#define D_STEER (0.4f * 0.03f)

#define ROWS 64          // rows per tile (= lanes per wave)
#define NT   128         // threads per block = 2 waves, both compute all rows
#define PAD  31          // float4 stride per row in LDS (30 + 1 pad)

typedef float f32x2 __attribute__((ext_vector_type(2)));
typedef float f32x4 __attribute__((ext_vector_type(4)));

__global__ __launch_bounds__(NT) void ccdec_kernel(
    const float* __restrict__ z,
    const float* __restrict__ init_state,
    float* __restrict__ out,
    int B)
{
    // Both waves compute ALL 64 rows redundantly and write bit-identical
    // values to the same LDS addresses -> each wave's own in-order
    // write->read (lgkmcnt) ordering suffices; NO barrier anywhere.
    // One-shot block: stores drain while the next block launches (HW
    // block-level pipelining -- persistent loops measured slower, R6-R8).
    __shared__ f32x4 lds[ROWS * PAD];   // 31744 B -> 5 blocks/CU = 10 waves/CU

    const int tid  = threadIdx.x;
    const int lane = tid & 63;          // row index within tile
    const int tile = blockIdx.x;

    int b  = tile * ROWS + lane;
    bool valid = (b < B);
    int bb = valid ? b : (B - 1);

    // ---- loads (both waves load the same rows; 2nd wave hits L2) ----
    f32x2 zv  = *(reinterpret_cast<const f32x2*>(z) + (size_t)bb);
    const f32x2* stp = reinterpret_cast<const f32x2*>(init_state) + 3ull * (size_t)bb;
    f32x2 s01 = stp[0];
    f32x2 s23 = stp[1];
    f32x2 s45 = stp[2];

    float x   = s01.x;
    float y   = s01.y;
    float psi = s23.x;
    float v   = s23.y;
    float last_st = s45.y;   // init_state[:,5]

    // ---- steering / pedal preamble (mirror clip_by_tensor semantics) ----
    float steering = zv.y * 0.5f;
    float tmin = last_st - D_STEER;
    float tmax = last_st + D_STEER;
    float r = (steering > tmin) ? steering : ((steering < tmin) ? tmin : 0.0f);
    r = (r <= tmax) ? r : tmax;
    steering = fminf(fmaxf(r, -0.5f), 0.5f);

    float pedal = zv.x * 2.5f;
    float beta  = fminf(fmaxf(steering, -0.5f), 0.5f);
    float a_t   = fminf(fmaxf(pedal, -2.5f), 2.5f);
    float tan_beta = __tanf(beta);
    float dpsi_k   = tan_beta * (1.0f / 2.5f) * DT;
    float adt      = a_t * DT;

    bool full_tile = ((tile + 1) * ROWS <= B);

    if (full_tile) {
        // ---- compute all 30 steps into LDS (both waves, same values) ----
        #pragma unroll
        for (int t = 0; t < SEQ_LEN; ++t) {
            float v1 = fminf(fmaxf(v + adt, 0.0f), 10.0f);
            psi = v * dpsi_k + psi;          // uses OLD v
            float s, c;
            __sincosf(psi, &s, &c);
            x = v1 * c * DT + x;
            y = v1 * s * DT + y;
            v = v1;
            f32x4 o; o.x = x; o.y = y; o.z = psi; o.w = v;
            lds[lane * PAD + t] = o;
        }

        // ---- stream tile out flat across BOTH waves: 15 wave-stores each,
        //      every store = 16 full aligned 64B lines ----
        f32x4* outp4 = reinterpret_cast<f32x4*>(out) + (size_t)tile * ROWS * SEQ_LEN;
        #pragma unroll
        for (int m = 0; m < SEQ_LEN / 2; ++m) {
            int f  = tid + m * NT;           // 0 .. 1919, contiguous per block
            int rr = f / SEQ_LEN;            // row within tile
            int jj = f - rr * SEQ_LEN;       // step
            outp4[f] = lds[rr * PAD + jj];
        }
    } else {
        // partial tile (not hit for B % 64 == 0): wave 0 does direct stores
        if (valid && tid < 64) {
            f32x4* outp = reinterpret_cast<f32x4*>(out) + (size_t)b * SEQ_LEN;
            #pragma unroll
            for (int t = 0; t < SEQ_LEN; ++t) {
                float v1 = fminf(fmaxf(v + adt, 0.0f), 10.0f);
                psi = v * dpsi_k + psi;
                float s, c;
                __sincosf(psi, &s, &c);
                x = v1 * c * DT + x;
                y = v1 * s * DT + y;
                v = v1;
                f32x4 o; o.x = x; o.y = y; o.z = psi; o.w = v;
                outp[t] = o;
            }
        }
    }
}

extern "C" void kernel_launch(void* const* d_in, const int* in_sizes, int n_in,
                              void* d_out, int out_size, void* d_ws, size_t ws_size,
                              hipStream_t stream)
{
    const float* z          = (const float*)d_in[0];   // (B, 2) f32
    const float* init_state = (const float*)d_in[1];   // (B, 6) f32
    float* out = (float*)d_out;                        // (B, 30, 4) f32

    int B = in_sizes[0] / 2;
    int ntiles = (B + ROWS - 1) / ROWS;
    ccdec_kernel<<<ntiles, NT, 0, stream>>>(z, init_state, out, B);
}